// Round 3
// baseline (529.491 us; speedup 1.0000x reference)
//
#include <hip/hip_runtime.h>

// SeesawLoss on MI355X — R6.
// Inputs: d_in[0] = cls_score fp32 (8,16,512,512), d_in[1] = labels i32 (8,512,512),
//         d_in[2] = cum_samples fp32 (16). Output: d_out[0] = scalar loss fp32.
// ws layout (uint32 words):
//   [0 .. 255]     histogram, cacheline-spread: count for class c at word c*16
//   [256 .. 1279]  64 accumulator pairs, pair i at words 256 + i*16 (+0 nll, +1 mask)
//   [1280]         seesaw done-counter (fused final reduction)
//   [1281]         hist done-counter (plog tail)
//   [1344 .. 1359] plog[16] = P * log(clip(hist + cum, 1, inf))
// History:
//  R3 (209 us): 1px/thread, loads clumped (by lucky structure), serial histp->barrier
//    ->loads prologue = two latency chains.
//  R4 (306 us): 4px float4 — compiler SANK the load clump below the barrier (VGPR=52)
//    to chase occupancy -> MLP destroyed.
//  R5 (528 us): barrier removed, but with nothing keeping l[16] live the compiler
//    strip-mined load->use (VGPR=16!) -> 16 SERIAL latencies/pixel, 361 us.
//  Lesson: hipcc sinks independent global loads to uses unless forced. R6 pins the
//  17-load clump with an empty asm volatile "+v" barrier (rule-17 liveness idiom):
//  all loads issued together, one vmcnt drain, no prologue dependency at all.

constexpr int   kC       = 16;
constexpr int   kHW      = 512 * 512;              // 2^18
constexpr float kP       = 0.8f;                   // mitigation exponent
constexpr float kLogEps  = -4.605170185988091f;    // ln(0.01)
constexpr int   kNAcc    = 64;                     // spread accumulator pairs
constexpr int   kCtrSee  = 256 + kNAcc * 16;       // word 1280
constexpr int   kCtrHist = kCtrSee + 1;            // word 1281
constexpr int   kPlogW   = 1344;                   // 64 B-aligned plog region

__global__ __launch_bounds__(256) void init_ws_k(unsigned int* ws) {
    for (int i = threadIdx.x; i < kPlogW + 16; i += 256) ws[i] = 0u;
}

// 512 blocks (2/CU): block covers 16 KB of labels, 4 int4/thread hoisted.
// Tail: last block computes plog[16] once, so seesaw_k needs no histp prologue.
__global__ __launch_bounds__(256) void hist_k(const int4* __restrict__ lab4,
                                              const float* __restrict__ cum_in,
                                              unsigned int* __restrict__ ws) {
    int base = blockIdx.x * 1024 + threadIdx.x;
    int4 v[4];
    #pragma unroll
    for (int j = 0; j < 4; ++j) v[j] = lab4[base + j * 256];   // contiguous 4 KB per iter
    asm volatile("" : "+v"(v[0].x), "+v"(v[0].y), "+v"(v[0].z), "+v"(v[0].w),
                      "+v"(v[1].x), "+v"(v[1].y), "+v"(v[1].z), "+v"(v[1].w),
                      "+v"(v[2].x), "+v"(v[2].y), "+v"(v[2].z), "+v"(v[2].w),
                      "+v"(v[3].x), "+v"(v[3].y), "+v"(v[3].z), "+v"(v[3].w));
    int cnt[16];
    #pragma unroll
    for (int c = 0; c < 16; ++c) cnt[c] = 0;
    #pragma unroll
    for (int j = 0; j < 4; ++j) {
        #pragma unroll
        for (int c = 0; c < 16; ++c)
            cnt[c] += (v[j].x == c) + (v[j].y == c) + (v[j].z == c) + (v[j].w == c);
    }
    #pragma unroll
    for (int c = 0; c < 16; ++c) {
        int x = cnt[c];
        #pragma unroll
        for (int off = 32; off > 0; off >>= 1) x += __shfl_down(x, off);
        cnt[c] = x;
    }
    __shared__ unsigned int sh[4 * 16];
    __shared__ int s_last;
    int wave = threadIdx.x >> 6, lane = threadIdx.x & 63;
    if (lane == 0) {
        #pragma unroll
        for (int c = 0; c < 16; ++c) sh[wave * 16 + c] = (unsigned)cnt[c];
    }
    __syncthreads();
    int t = threadIdx.x;
    if (t < 16)   // per-class slots 64 B apart
        atomicAdd(&ws[t * 16], sh[t] + sh[16 + t] + sh[32 + t] + sh[48 + t]);
    __syncthreads();                       // this block's atomics are issued
    if (t == 0) {
        __threadfence();                   // release our histogram contribution
        unsigned d = atomicAdd(ws + kCtrHist, 1u);
        s_last = (d == gridDim.x - 1) ? 1 : 0;
    }
    __syncthreads();
    if (s_last && t < 16) {                // last block: histogram is complete
        __threadfence();                   // acquire side
        unsigned h = __hip_atomic_load(ws + t * 16,
                                       __ATOMIC_RELAXED, __HIP_MEMORY_SCOPE_AGENT);
        float cc = fmaxf((float)h + cum_in[t], 1.0f);      // clip(cum, 1, inf)
        ((float*)ws)[kPlogW + t] = kP * __logf(cc);
    }
}

// 1 pixel/thread, 8192 blocks x 256 threads. No barrier, no pre-load dependency;
// the 17-load clump is PINNED live via an empty asm so the scheduler cannot
// strip-mine it (R5's failure). plog is a uniform 64 B read off the critical path.
__global__ __launch_bounds__(256, 4) void seesaw_k(const float* __restrict__ cls,
                                                   const int*   __restrict__ labels,
                                                   const float* __restrict__ plogp,
                                                   unsigned int* __restrict__ ws,
                                                   float* __restrict__ out) {
    __shared__ float s_red[8];
    __shared__ int   s_last;
    int t  = threadIdx.x;
    int px = blockIdx.x * 256 + t;                 // grid exactly covers M
    int b  = px >> 18;
    int hw = px & (kHW - 1);
    const float* pbase = cls + (long long)b * kC * kHW + hw;

    float l[16];
    #pragma unroll
    for (int c = 0; c < 16; ++c) l[c] = pbase[(long long)c * kHW];
    int lab = labels[px];
    // Liveness pin: all 17 loads issued as one clump, one vmcnt drain here.
    asm volatile("" : "+v"(l[0]),  "+v"(l[1]),  "+v"(l[2]),  "+v"(l[3]),
                      "+v"(l[4]),  "+v"(l[5]),  "+v"(l[6]),  "+v"(l[7]),
                      "+v"(l[8]),  "+v"(l[9]),  "+v"(l[10]), "+v"(l[11]),
                      "+v"(l[12]), "+v"(l[13]), "+v"(l[14]), "+v"(l[15]),
                      "+v"(lab));

    float pl[16];
    #pragma unroll
    for (int c = 0; c < 16; ++c) pl[c] = plogp[c];  // uniform addr -> scalar loads

    float m1   = l[0];
    float llab = l[0];                              // select chains, no dynamic index
    float plab = pl[0];
    #pragma unroll
    for (int c = 1; c < 16; ++c) {
        m1 = fmaxf(m1, l[c]);
        if (c == lab) { llab = l[c]; plab = pl[c]; }
    }
    float s = 0.0f;
    #pragma unroll
    for (int c = 0; c < 16; ++c) s += __expf(l[c] - m1);
    // log(score_mat[c]) = l[c] - K, K = max(llab, m1 + log s + log EPS)
    float K = fmaxf(llab, m1 + __logf(s) + kLogEps);

    float m2 = -3.0e38f;
    #pragma unroll
    for (int c = 0; c < 16; ++c) {
        // adj = l + log(mit) + log(comp); both clamp to 0 at c==lab -> adj==llab
        float a = l[c] + fminf(0.0f, pl[c] - plab)
                       + fmaxf(0.0f, 2.0f * (l[c] - K));
        l[c] = a;
        m2 = fmaxf(m2, a);
    }
    float s2 = 0.0f;
    #pragma unroll
    for (int c = 0; c < 16; ++c) s2 += __expf(l[c] - m2);
    float nll = m2 + __logf(s2) - llab;             // -log_softmax(adj)[lab]

    float lsum = 0.0f, lcnt = 0.0f;
    if (lab != 0) { lsum = nll; lcnt = 1.0f; }      // ignore_index = 0
    #pragma unroll
    for (int off = 32; off > 0; off >>= 1) {
        lsum += __shfl_down(lsum, off);
        lcnt += __shfl_down(lcnt, off);
    }
    int wave = t >> 6, lane = t & 63;
    if (lane == 0) { s_red[wave] = lsum; s_red[4 + wave] = lcnt; }
    __syncthreads();
    if (t == 0) {
        float* pair = (float*)ws + 256 + (blockIdx.x & (kNAcc - 1)) * 16;  // 64 B-spread
        atomicAdd(&pair[0], s_red[0] + s_red[1] + s_red[2] + s_red[3]);
        atomicAdd(&pair[1], s_red[4] + s_red[5] + s_red[6] + s_red[7]);
        __threadfence();                                                   // release
        unsigned done = atomicAdd(ws + kCtrSee, 1u);
        s_last = (done == gridDim.x - 1) ? 1 : 0;
    }
    __syncthreads();
    if (s_last && t < 64) {                         // fused final reduction (last block)
        __threadfence();                            // acquire side
        float a  = __hip_atomic_load((float*)ws + 256 + t * 16,
                                     __ATOMIC_RELAXED, __HIP_MEMORY_SCOPE_AGENT);
        float bb = __hip_atomic_load((float*)ws + 256 + t * 16 + 1,
                                     __ATOMIC_RELAXED, __HIP_MEMORY_SCOPE_AGENT);
        #pragma unroll
        for (int off = 32; off > 0; off >>= 1) {
            a  += __shfl_down(a, off);
            bb += __shfl_down(bb, off);
        }
        if (t == 0) out[0] = a / bb;
    }
}

extern "C" void kernel_launch(void* const* d_in, const int* in_sizes, int n_in,
                              void* d_out, int out_size, void* d_ws, size_t ws_size,
                              hipStream_t stream) {
    const float* cls    = (const float*)d_in[0];
    const int*   labels = (const int*)d_in[1];
    const float* cum_in = (const float*)d_in[2];
    float* out = (float*)d_out;
    unsigned int* ws = (unsigned int*)d_ws;

    int M  = in_sizes[1];        // 2,097,152 pixels
    int n4 = M / 4;

    init_ws_k<<<1, 256, 0, stream>>>(ws);
    hist_k<<<n4 / 1024, 256, 0, stream>>>((const int4*)labels, cum_in, ws);
    seesaw_k<<<M / 256, 256, 0, stream>>>(cls, labels,
                                          (const float*)ws + kPlogW, ws, out);
}

// Round 5
// 205.422 us; speedup vs baseline: 2.5776x; 2.5776x over previous
//
#include <hip/hip_runtime.h>

// SeesawLoss on MI355X — R8 (== R7 resubmitted; R4-round failure was container
// infra, not the kernel: no compile/test error, and ws footprint 96 KB vs the
// ~512 MiB d_ws the harness poison-fills).
// Inputs: d_in[0] = cls_score fp32 (8,16,512,512), d_in[1] = labels i32 (8,512,512),
//         d_in[2] = cum_samples fp32 (16). Output: d_out[0] = scalar loss fp32.
//
// History / evidence:
//  R3 (209 us): seesaw ~45 us. Separate final_k, NO fences/counters.
//  R4 (306 us): introduced fused finalize (threadfence + single-word done-counter,
//     whole block waits for the returned value). seesaw 148 us @ 2048 blocks.
//  R5/R6 (528/529 us): same tail @ 8192 blocks -> seesaw 361/367 us.
//  R6 decisive: asm pin gave 16 clumped live loads (VGPR 16->20) with ZERO perf
//     change -> load scheduling is NOT the bottleneck. The tail is: agent-scope
//     fence (L2 writeback on gfx950) + 8192-way same-word atomic-with-return that
//     the whole block waits on ~= 330 us of serialized critical path. WRITE_SIZE
//     scaled exactly with block count (96 B/block of forced line writebacks).
//  R7/R8: zero atomics, zero fences anywhere. Kernel-launch boundaries provide all
//     ordering. hist stores per-block partials; plog_k folds them; seesaw stores
//     one float2 per block; final_k reduces 8192 pairs. No region is read before
//     written -> init_ws_k deleted too.
//
// ws layout (uint32 words):
//   [0 .. 8191]      hist partials: block b, class c at word b*16+c   (32 KB)
//   [8192 .. 8207]   plog[16] = P * log(clip(hist_total + cum, 1, inf))
//   [8256 .. 24639]  per-block pairs: float2 {nll_sum, cnt_sum} at pair blockIdx
//                    (base byte 33024, 16B-aligned for float4 reads in final_k)

constexpr int   kC      = 16;
constexpr int   kHW     = 512 * 512;               // 2^18
constexpr float kP      = 0.8f;                    // mitigation exponent
constexpr float kLogEps = -4.605170185988091f;     // ln(0.01)
constexpr int   kPartW  = 0;                       // hist partials base word
constexpr int   kPlogW  = 8192;                    // plog base word
constexpr int   kPairW  = 8256;                    // pairs base word (16B aligned)

// 512 blocks (2/CU): block covers 16 KB of labels, 4 int4/thread, pinned clump.
// Tail: plain stores of the block's 16 counts to its private slot. No atomics.
__global__ __launch_bounds__(256) void hist_k(const int4* __restrict__ lab4,
                                              unsigned int* __restrict__ ws) {
    int base = blockIdx.x * 1024 + threadIdx.x;
    int4 v[4];
    #pragma unroll
    for (int j = 0; j < 4; ++j) v[j] = lab4[base + j * 256];   // contiguous 4 KB per iter
    asm volatile("" : "+v"(v[0].x), "+v"(v[0].y), "+v"(v[0].z), "+v"(v[0].w),
                      "+v"(v[1].x), "+v"(v[1].y), "+v"(v[1].z), "+v"(v[1].w),
                      "+v"(v[2].x), "+v"(v[2].y), "+v"(v[2].z), "+v"(v[2].w),
                      "+v"(v[3].x), "+v"(v[3].y), "+v"(v[3].z), "+v"(v[3].w));
    int cnt[16];
    #pragma unroll
    for (int c = 0; c < 16; ++c) cnt[c] = 0;
    #pragma unroll
    for (int j = 0; j < 4; ++j) {
        #pragma unroll
        for (int c = 0; c < 16; ++c)
            cnt[c] += (v[j].x == c) + (v[j].y == c) + (v[j].z == c) + (v[j].w == c);
    }
    #pragma unroll
    for (int c = 0; c < 16; ++c) {
        int x = cnt[c];
        #pragma unroll
        for (int off = 32; off > 0; off >>= 1) x += __shfl_down(x, off);
        cnt[c] = x;
    }
    __shared__ unsigned int sh[4 * 16];
    int wave = threadIdx.x >> 6, lane = threadIdx.x & 63;
    if (lane == 0) {
        #pragma unroll
        for (int c = 0; c < 16; ++c) sh[wave * 16 + c] = (unsigned)cnt[c];
    }
    __syncthreads();
    int t = threadIdx.x;
    if (t < 16)   // private slot, plain store
        ws[kPartW + blockIdx.x * 16 + t] = sh[t] + sh[16 + t] + sh[32 + t] + sh[48 + t];
}

// 1 block. Folds 512x16 partials -> plog[16]. Kernel boundary = ordering.
__global__ __launch_bounds__(256) void plog_k(const float* __restrict__ cum_in,
                                              unsigned int* __restrict__ ws) {
    __shared__ float sh[256];                      // [group][class], linear = t
    int t = threadIdx.x;
    int c = t & 15, g = t >> 4;                    // 16 groups x 16 classes
    unsigned s = 0;
    #pragma unroll 4
    for (int i = 0; i < 32; ++i)                   // group g sums 32 of 512 blocks
        s += ws[kPartW + (g * 32 + i) * 16 + c];
    sh[t] = (float)s;                              // exact: counts <= 2^21
    __syncthreads();
    if (t < 16) {
        float tot = 0.0f;
        #pragma unroll
        for (int gg = 0; gg < 16; ++gg) tot += sh[gg * 16 + t];
        float cc = fmaxf(tot + cum_in[t], 1.0f);   // clip(cum, 1, inf)
        ((float*)ws)[kPlogW + t] = kP * __logf(cc);
    }
}

// 1 pixel/thread, 8192 blocks x 256 threads. Loads first (no prologue dependency),
// 17-load clump pinned live. Tail: ONE plain float2 store per block. No atomics,
// no fences, no waiting.
__global__ __launch_bounds__(256, 4) void seesaw_k(const float* __restrict__ cls,
                                                   const int*   __restrict__ labels,
                                                   const float* __restrict__ plogp,
                                                   float* __restrict__ pairs) {
    __shared__ float s_red[8];
    int t  = threadIdx.x;
    int px = blockIdx.x * 256 + t;                 // grid exactly covers M
    int b  = px >> 18;
    int hw = px & (kHW - 1);
    const float* pbase = cls + (long long)b * kC * kHW + hw;

    float l[16];
    #pragma unroll
    for (int c = 0; c < 16; ++c) l[c] = pbase[(long long)c * kHW];
    int lab = labels[px];
    // Liveness pin: all 17 loads issued as one clump, one vmcnt drain here.
    asm volatile("" : "+v"(l[0]),  "+v"(l[1]),  "+v"(l[2]),  "+v"(l[3]),
                      "+v"(l[4]),  "+v"(l[5]),  "+v"(l[6]),  "+v"(l[7]),
                      "+v"(l[8]),  "+v"(l[9]),  "+v"(l[10]), "+v"(l[11]),
                      "+v"(l[12]), "+v"(l[13]), "+v"(l[14]), "+v"(l[15]),
                      "+v"(lab));

    float pl[16];
    #pragma unroll
    for (int c = 0; c < 16; ++c) pl[c] = plogp[c];  // uniform addr -> scalar loads

    float m1   = l[0];
    float llab = l[0];                              // select chains, no dynamic index
    float plab = pl[0];
    #pragma unroll
    for (int c = 1; c < 16; ++c) {
        m1 = fmaxf(m1, l[c]);
        if (c == lab) { llab = l[c]; plab = pl[c]; }
    }
    float s = 0.0f;
    #pragma unroll
    for (int c = 0; c < 16; ++c) s += __expf(l[c] - m1);
    // log(score_mat[c]) = l[c] - K, K = max(llab, m1 + log s + log EPS)
    float K = fmaxf(llab, m1 + __logf(s) + kLogEps);

    float m2 = -3.0e38f;
    #pragma unroll
    for (int c = 0; c < 16; ++c) {
        // adj = l + log(mit) + log(comp); both clamp to 0 at c==lab -> adj==llab
        float a = l[c] + fminf(0.0f, pl[c] - plab)
                       + fmaxf(0.0f, 2.0f * (l[c] - K));
        l[c] = a;
        m2 = fmaxf(m2, a);
    }
    float s2 = 0.0f;
    #pragma unroll
    for (int c = 0; c < 16; ++c) s2 += __expf(l[c] - m2);
    float nll = m2 + __logf(s2) - llab;             // -log_softmax(adj)[lab]

    float lsum = 0.0f, lcnt = 0.0f;
    if (lab != 0) { lsum = nll; lcnt = 1.0f; }      // ignore_index = 0
    #pragma unroll
    for (int off = 32; off > 0; off >>= 1) {
        lsum += __shfl_down(lsum, off);
        lcnt += __shfl_down(lcnt, off);
    }
    int wave = t >> 6, lane = t & 63;
    if (lane == 0) { s_red[wave] = lsum; s_red[4 + wave] = lcnt; }
    __syncthreads();
    if (t == 0) {                                   // one plain 8B store per block
        float2 pr;
        pr.x = s_red[0] + s_red[1] + s_red[2] + s_red[3];
        pr.y = s_red[4] + s_red[5] + s_red[6] + s_red[7];
        ((float2*)pairs)[blockIdx.x] = pr;
    }
}

// 1 block, 256 threads: reduce 8192 float2 pairs (64 KB) -> loss.
__global__ __launch_bounds__(256) void final_k(const float* __restrict__ pairs,
                                               float* __restrict__ out) {
    __shared__ float s_red[8];
    int t = threadIdx.x;
    const float4* p4 = (const float4*)pairs;       // 4096 float4 = 8192 pairs
    float4 v[16];
    #pragma unroll
    for (int i = 0; i < 16; ++i) v[i] = p4[t + i * 256];
    asm volatile("" : "+v"(v[0].x),  "+v"(v[1].x),  "+v"(v[2].x),  "+v"(v[3].x),
                      "+v"(v[4].x),  "+v"(v[5].x),  "+v"(v[6].x),  "+v"(v[7].x),
                      "+v"(v[8].x),  "+v"(v[9].x),  "+v"(v[10].x), "+v"(v[11].x),
                      "+v"(v[12].x), "+v"(v[13].x), "+v"(v[14].x), "+v"(v[15].x));
    float a = 0.0f, bb = 0.0f;
    #pragma unroll
    for (int i = 0; i < 16; ++i) { a += v[i].x + v[i].z; bb += v[i].y + v[i].w; }
    #pragma unroll
    for (int off = 32; off > 0; off >>= 1) {
        a  += __shfl_down(a, off);
        bb += __shfl_down(bb, off);
    }
    int wave = t >> 6, lane = t & 63;
    if (lane == 0) { s_red[wave] = a; s_red[4 + wave] = bb; }
    __syncthreads();
    if (t == 0)
        out[0] = (s_red[0] + s_red[1] + s_red[2] + s_red[3]) /
                 (s_red[4] + s_red[5] + s_red[6] + s_red[7]);
}

extern "C" void kernel_launch(void* const* d_in, const int* in_sizes, int n_in,
                              void* d_out, int out_size, void* d_ws, size_t ws_size,
                              hipStream_t stream) {
    const float* cls    = (const float*)d_in[0];
    const int*   labels = (const int*)d_in[1];
    const float* cum_in = (const float*)d_in[2];
    float* out = (float*)d_out;
    unsigned int* ws = (unsigned int*)d_ws;

    int M  = in_sizes[1];        // 2,097,152 pixels
    int n4 = M / 4;

    hist_k  <<<n4 / 1024, 256, 0, stream>>>((const int4*)labels, ws);
    plog_k  <<<1,         256, 0, stream>>>(cum_in, ws);
    seesaw_k<<<M / 256,   256, 0, stream>>>(cls, labels,
                                            (const float*)ws + kPlogW,
                                            (float*)ws + kPairW);
    final_k <<<1,         256, 0, stream>>>((const float*)ws + kPairW, out);
}